// Round 5
// baseline (578.082 us; speedup 1.0000x reference)
//
#include <hip/hip_runtime.h>
#include <stdint.h>

// ---------------- problem constants ----------------
#define TOK    4096
#define DMODEL 1024
#define FDIM   2048
#define NEXP   8
#define MAXP   9216            // 2*TOK + 8*128 worst-case segment padding
#define MAXT   72              // MAXP / 128 row tiles
#define OUT_MAIN (TOK * DMODEL)

// meta int indices
#define IDX_NT  24
#define IDX_TE  32
#define IDX_TR  112

// ws byte offsets
#define OFF_META 0
#define OFF_TKE  1024
#define OFF_TKW  33792
#define OFF_PTOK 66560
#define OFF_PW   103424
#define OFF_XG   140288            // [MAXP][1024] bf16
#define OFF_H    19014656          // [MAXP][2048] bf16
#define OFF_WGB  56763392          // [E][F][D] bf16
#define OFF_WUB  90317824          // [E][F][D] bf16
#define OFF_WDB  123872256         // [E][D][F] bf16
#define OFF_PV   OFF_WGB           // [MAXP][1024] fp32 — aliases wgb+wub (dead after k_gu)
#define OFF_RPOS 157426688
#define WS_NEED  157459456

typedef __attribute__((ext_vector_type(8)))  __bf16 bf16x8;
typedef __attribute__((ext_vector_type(8)))  unsigned short u16x8;
typedef __attribute__((ext_vector_type(4)))  unsigned short u16x4;
typedef __attribute__((ext_vector_type(16))) float f32x16;

__device__ __forceinline__ unsigned short f2bf(float f) {
  unsigned u = __builtin_bit_cast(unsigned, f);
  u += 0x7fffu + ((u >> 16) & 1u);          // RNE
  return (unsigned short)(u >> 16);
}

__device__ __forceinline__ bf16x8 ld_frag(const unsigned short* p) {
  return __builtin_bit_cast(bf16x8, *(const u16x8*)p);
}

// ---------------- fused prep: weight conv + router logits + per-token top-2 --------
// blocks [0,24576): conv; [24576,25600): router (fp64 accum) + sparsemixer on lane 0
__global__ void k_prep(const float* __restrict__ wg, const float* __restrict__ wu,
                       const float* __restrict__ wd, unsigned short* __restrict__ wgb,
                       unsigned short* __restrict__ wub, unsigned short* __restrict__ wdb,
                       const float* __restrict__ x, const float* __restrict__ gw,
                       float* __restrict__ logits, int* __restrict__ tk_e,
                       float* __restrict__ tk_w, int pre) {
  int b = blockIdx.x;
  if (b < 24576) {
    if (!pre) return;
    const float* src; unsigned short* dst; int bb;
    if (b < 8192)       { src = wg; dst = wgb; bb = b; }
    else if (b < 16384) { src = wu; dst = wub; bb = b - 8192; }
    else                { src = wd; dst = wdb; bb = b - 16384; }
    size_t i = ((size_t)bb * 256 + threadIdx.x) * 8;
    float4 a = *(const float4*)(src + i);
    float4 c = *(const float4*)(src + i + 4);
    u16x8 v = {f2bf(a.x), f2bf(a.y), f2bf(a.z), f2bf(a.w),
               f2bf(c.x), f2bf(c.y), f2bf(c.z), f2bf(c.w)};
    *(u16x8*)(dst + i) = v;
    return;
  }
  int lane = threadIdx.x & 63;
  int t = (b - 24576) * 4 + (threadIdx.x >> 6);
  double acc[NEXP];
#pragma unroll
  for (int e = 0; e < NEXP; ++e) acc[e] = 0.0;
  const float* xp = x + (size_t)t * DMODEL;
  for (int i = 0; i < DMODEL / 64; ++i) {
    int d = i * 64 + lane;
    float xv = xp[d];
#pragma unroll
    for (int e = 0; e < NEXP; ++e) acc[e] += (double)xv * (double)gw[e * DMODEL + d];
  }
  float s[NEXP];
#pragma unroll
  for (int e = 0; e < NEXP; ++e) {
    double v = acc[e];
#pragma unroll
    for (int off = 32; off > 0; off >>= 1) v += __shfl_down(v, off, 64);
    if (lane == 0) { s[e] = (float)v; logits[t * NEXP + e] = (float)v; }
  }
  if (lane == 0) {
    float max1 = s[0]; int ind1 = 0;
#pragma unroll
    for (int e = 1; e < NEXP; ++e) if (s[e] > max1) { max1 = s[e]; ind1 = e; }
    float sum1 = 0.f;
#pragma unroll
    for (int e = 0; e < NEXP; ++e) {
      float f = fmaxf(fabsf(s[e]), max1);
      if (!((max1 - s[e]) / f > 0.02f)) sum1 += expf(s[e] - max1);
    }
    float max2 = -3.4e38f; int ind2 = 0;
#pragma unroll
    for (int e = 0; e < NEXP; ++e) if (e != ind1 && s[e] > max2) { max2 = s[e]; ind2 = e; }
    float sum2 = 0.f;
#pragma unroll
    for (int e = 0; e < NEXP; ++e) {
      if (e == ind1) continue;
      float f = fmaxf(fabsf(s[e]), max2);
      if (!((max2 - s[e]) / f > 0.02f)) sum2 += expf(s[e] - max2);
    }
    tk_e[2 * t] = ind1; tk_e[2 * t + 1] = ind2;
    tk_w[2 * t] = 1.f / sum1; tk_w[2 * t + 1] = 1.f / sum2;
  }
}

// ---------------- count + scan + scatter (single block, 256 thr) -------------------
__global__ __launch_bounds__(256) void k_route2(
    const int* __restrict__ tk_e, const float* __restrict__ tk_w,
    int* __restrict__ meta, int* __restrict__ ptok, float* __restrict__ pw,
    int* __restrict__ rpos) {
  __shared__ int cnt[NEXP], cur[NEXP], seg[NEXP];
  int tid = threadIdx.x;
  if (tid < NEXP) { cnt[tid] = 0; cur[tid] = 0; }
  for (int r = tid; r < MAXP; r += 256) ptok[r] = -1;
  __syncthreads();
  int e1[16], e2[16];
#pragma unroll
  for (int j = 0; j < 16; ++j) {
    int t = tid * 16 + j;
    e1[j] = tk_e[2 * t]; e2[j] = tk_e[2 * t + 1];
  }
#pragma unroll
  for (int e = 0; e < NEXP; ++e) {
    int lc = 0;
#pragma unroll
    for (int j = 0; j < 16; ++j) lc += (e1[j] == e) + (e2[j] == e);
    if (lc) atomicAdd(&cnt[e], lc);
  }
  __syncthreads();
  if (tid == 0) {
    int off = 0, nt2 = 0;
    for (int e = 0; e < NEXP; ++e) {
      seg[e] = off;
      int tiles = (cnt[e] + 127) >> 7;
      for (int j = 0; j < tiles; ++j) {
        meta[IDX_TE + nt2] = e;
        meta[IDX_TR + nt2] = off + (j << 7);
        ++nt2;
      }
      off += tiles << 7;
    }
    meta[IDX_NT] = nt2;
  }
  __syncthreads();
#pragma unroll
  for (int e = 0; e < NEXP; ++e) {
    int lc = 0;
#pragma unroll
    for (int j = 0; j < 16; ++j) lc += (e1[j] == e) + (e2[j] == e);
    if (!lc) continue;
    int base = seg[e] + atomicAdd(&cur[e], lc);
#pragma unroll
    for (int j = 0; j < 16; ++j) {
      int t = tid * 16 + j;
      if (e1[j] == e) {
        int r = base++;
        ptok[r] = t; pw[r] = tk_w[2 * t]; rpos[2 * t] = r;
      }
      if (e2[j] == e) {
        int r = base++;
        ptok[r] = t; pw[r] = tk_w[2 * t + 1]; rpos[2 * t + 1] = r;
      }
    }
  }
}

// ---------------- gather x rows (fp32 -> bf16) in pair order; pads -> 0 ------------
__global__ void k_gather(const float* __restrict__ x, const int* __restrict__ ptok,
                         unsigned short* __restrict__ xg) {
  int r = blockIdx.x;
  int t = ptok[r];
  int c = threadIdx.x << 2;
  unsigned short o0 = 0, o1 = 0, o2 = 0, o3 = 0;
  if (t >= 0) {
    float4 v = *(const float4*)(x + ((size_t)t << 10) + c);
    o0 = f2bf(v.x); o1 = f2bf(v.y); o2 = f2bf(v.z); o3 = f2bf(v.w);
  }
  u16x4 o = {o0, o1, o2, o3};
  *(u16x4*)(xg + ((size_t)r << 10) + c) = o;
}

// ---------------- fused gate+up GEMM, 32x32x16, tile 128x64, BK=64 -----------------
// PRE: VGPR-prefetch pipeline (load k+1 -> regs, MFMA k from LDS, barrier, ds_write)
template <bool PRE>
__global__ __launch_bounds__(256, 3) void k_gu(
    const unsigned short* __restrict__ xg,
    const float* __restrict__ wg32, const float* __restrict__ wu32,
    const unsigned short* __restrict__ wgb, const unsigned short* __restrict__ wub,
    unsigned short* __restrict__ h, const int* __restrict__ meta) {
  int nt = meta[IDX_NT];
  int rt = blockIdx.y;
  if (rt >= nt) return;
  int e = meta[IDX_TE + rt];
  int row0 = meta[IDX_TR + rt];
  int n0 = blockIdx.x * 64;

  __shared__ __align__(16) unsigned short As[8192], Bg[4096], Bu[4096];

  int tid = threadIdx.x, lane = tid & 63, w = tid >> 6;
  int wm = w & 1, wn = w >> 1;
  int l31 = lane & 31, lh = lane >> 5;

  f32x16 accg[2], accu[2];
#pragma unroll
  for (int i = 0; i < 2; ++i) {
#pragma unroll
    for (int r = 0; r < 16; ++r) { accg[i][r] = 0.f; accu[i][r] = 0.f; }
  }

  // A chunk c = msub*4 + kq; wave w stages msub=w, kq=0..3
  const unsigned short* Abase = xg + (size_t)(row0 + w * 32 + l31) * DMODEL + lh * 8;
  int c0 = w * 2, c1 = c0 + 1;        // B chunks c = nsub*4 + kq
  const unsigned short *G0, *G1, *U0, *U1;
  if constexpr (PRE) {
    const unsigned short* WgB = wgb + (size_t)e * FDIM * DMODEL;
    const unsigned short* WuB = wub + (size_t)e * FDIM * DMODEL;
    size_t o0 = (size_t)(n0 + ((c0 >> 2) << 5) + l31) * DMODEL + ((c0 & 3) << 4) + lh * 8;
    size_t o1 = (size_t)(n0 + ((c1 >> 2) << 5) + l31) * DMODEL + ((c1 & 3) << 4) + lh * 8;
    G0 = WgB + o0; G1 = WgB + o1; U0 = WuB + o0; U1 = WuB + o1;
  }

  if constexpr (PRE) {
    u16x8 pa[4], pg[2], pu[2];
    // prologue: stage step 0
#pragma unroll
    for (int i = 0; i < 4; ++i) pa[i] = *(const u16x8*)(Abase + i * 16);
    pg[0] = *(const u16x8*)G0; pg[1] = *(const u16x8*)G1;
    pu[0] = *(const u16x8*)U0; pu[1] = *(const u16x8*)U1;
#pragma unroll
    for (int i = 0; i < 4; ++i) *(u16x8*)&As[(w * 4 + i) * 512 + lane * 8] = pa[i];
    *(u16x8*)&Bg[c0 * 512 + lane * 8] = pg[0];
    *(u16x8*)&Bg[c1 * 512 + lane * 8] = pg[1];
    *(u16x8*)&Bu[c0 * 512 + lane * 8] = pu[0];
    *(u16x8*)&Bu[c1 * 512 + lane * 8] = pu[1];
    __syncthreads();
    for (int ks = 0; ks < DMODEL / 64; ++ks) {
      if (ks < DMODEL / 64 - 1) {
        int k1 = (ks + 1) * 64;
#pragma unroll
        for (int i = 0; i < 4; ++i) pa[i] = *(const u16x8*)(Abase + k1 + i * 16);
        pg[0] = *(const u16x8*)(G0 + k1); pg[1] = *(const u16x8*)(G1 + k1);
        pu[0] = *(const u16x8*)(U0 + k1); pu[1] = *(const u16x8*)(U1 + k1);
      }
#pragma unroll
      for (int kq = 0; kq < 4; ++kq) {
        bf16x8 a0 = ld_frag(&As[((wm * 2 + 0) * 4 + kq) * 512 + lane * 8]);
        bf16x8 a1 = ld_frag(&As[((wm * 2 + 1) * 4 + kq) * 512 + lane * 8]);
        bf16x8 vg = ld_frag(&Bg[(wn * 4 + kq) * 512 + lane * 8]);
        bf16x8 vu = ld_frag(&Bu[(wn * 4 + kq) * 512 + lane * 8]);
        accg[0] = __builtin_amdgcn_mfma_f32_32x32x16_bf16(a0, vg, accg[0], 0, 0, 0);
        accg[1] = __builtin_amdgcn_mfma_f32_32x32x16_bf16(a1, vg, accg[1], 0, 0, 0);
        accu[0] = __builtin_amdgcn_mfma_f32_32x32x16_bf16(a0, vu, accu[0], 0, 0, 0);
        accu[1] = __builtin_amdgcn_mfma_f32_32x32x16_bf16(a1, vu, accu[1], 0, 0, 0);
      }
      if (ks < DMODEL / 64 - 1) {
        __syncthreads();          // all reads of this step done; prefetch loads drained
#pragma unroll
        for (int i = 0; i < 4; ++i) *(u16x8*)&As[(w * 4 + i) * 512 + lane * 8] = pa[i];
        *(u16x8*)&Bg[c0 * 512 + lane * 8] = pg[0];
        *(u16x8*)&Bg[c1 * 512 + lane * 8] = pg[1];
        *(u16x8*)&Bu[c0 * 512 + lane * 8] = pu[0];
        *(u16x8*)&Bu[c1 * 512 + lane * 8] = pu[1];
        __syncthreads();
      }
    }
  } else {
    const float* Wg = wg32 + (size_t)e * FDIM * DMODEL;
    const float* Wu = wu32 + (size_t)e * FDIM * DMODEL;
    for (int ks = 0; ks < DMODEL / 64; ++ks) {
      int k0 = ks * 64;
      if (ks) __syncthreads();
      // A via fp32->bf16 from xg? xg already bf16 — stage via plain LDS writes
#pragma unroll
      for (int i = 0; i < 4; ++i) {
        u16x8 va = *(const u16x8*)(Abase + k0 + i * 16);
        *(u16x8*)&As[(w * 4 + i) * 512 + lane * 8] = va;
      }
#pragma unroll
      for (int i2 = 0; i2 < 2; ++i2) {
        int tau = tid + 256 * i2;
        int c = tau >> 6, l = tau & 63;
        int nrow = n0 + ((c >> 2) << 5) + (l & 31);
        int kk = k0 + ((c & 3) << 4) + ((l >> 5) << 3);
        const float* sg = Wg + (size_t)nrow * DMODEL + kk;
        const float* su = Wu + (size_t)nrow * DMODEL + kk;
        float4 g0 = *(const float4*)sg;
        float4 g1 = *(const float4*)(sg + 4);
        float4 u0 = *(const float4*)su;
        float4 u1 = *(const float4*)(su + 4);
        u16x8 vg = {f2bf(g0.x), f2bf(g0.y), f2bf(g0.z), f2bf(g0.w),
                    f2bf(g1.x), f2bf(g1.y), f2bf(g1.z), f2bf(g1.w)};
        u16x8 vu = {f2bf(u0.x), f2bf(u0.y), f2bf(u0.z), f2bf(u0.w),
                    f2bf(u1.x), f2bf(u1.y), f2bf(u1.z), f2bf(u1.w)};
        *(u16x8*)&Bg[c * 512 + l * 8] = vg;
        *(u16x8*)&Bu[c * 512 + l * 8] = vu;
      }
      __syncthreads();
#pragma unroll
      for (int kq = 0; kq < 4; ++kq) {
        bf16x8 a0 = ld_frag(&As[((wm * 2 + 0) * 4 + kq) * 512 + lane * 8]);
        bf16x8 a1 = ld_frag(&As[((wm * 2 + 1) * 4 + kq) * 512 + lane * 8]);
        bf16x8 vg = ld_frag(&Bg[(wn * 4 + kq) * 512 + lane * 8]);
        bf16x8 vu = ld_frag(&Bu[(wn * 4 + kq) * 512 + lane * 8]);
        accg[0] = __builtin_amdgcn_mfma_f32_32x32x16_bf16(a0, vg, accg[0], 0, 0, 0);
        accg[1] = __builtin_amdgcn_mfma_f32_32x32x16_bf16(a1, vg, accg[1], 0, 0, 0);
        accu[0] = __builtin_amdgcn_mfma_f32_32x32x16_bf16(a0, vu, accu[0], 0, 0, 0);
        accu[1] = __builtin_amdgcn_mfma_f32_32x32x16_bf16(a1, vu, accu[1], 0, 0, 0);
      }
    }
  }
  // epilogue: C/D layout col=lane&31, row=(r&3)+8*(r>>2)+4*lh
  int col = n0 + wn * 32 + l31;
#pragma unroll
  for (int mt = 0; mt < 2; ++mt) {
#pragma unroll
    for (int r = 0; r < 16; ++r) {
      int lrow = wm * 64 + mt * 32 + (r & 3) + ((r >> 2) << 3) + lh * 4;
      float gv = accg[mt][r], uv = accu[mt][r];
      float hv = gv * uv / (1.f + __expf(-gv));
      h[(size_t)(row0 + lrow) * FDIM + col] = f2bf(hv);
    }
  }
}

// ---------------- down GEMM: pv = h @ Wd^T, 32x32x16, tile 128x64, BK=64 -----------
template <bool PRE>
__global__ __launch_bounds__(256, 4) void k_down(
    const unsigned short* __restrict__ h, const float* __restrict__ wd32,
    const unsigned short* __restrict__ wdb, float* __restrict__ out,
    float* __restrict__ pv, const int* __restrict__ meta,
    const int* __restrict__ ptok, const float* __restrict__ pw) {
  int nt = meta[IDX_NT];
  int rt = blockIdx.y;
  if (rt >= nt) return;
  int e = meta[IDX_TE + rt];
  int row0 = meta[IDX_TR + rt];
  int d0 = blockIdx.x * 64;

  __shared__ __align__(16) unsigned short Ah[8192], Bd[4096];
  __shared__ int stok[128];
  __shared__ float sw[128];

  int tid = threadIdx.x, lane = tid & 63, w = tid >> 6;
  int wm = w & 1, wn = w >> 1;
  int l31 = lane & 31, lh = lane >> 5;

  if constexpr (!PRE) {
    if (tid < 128) { stok[tid] = ptok[row0 + tid]; sw[tid] = pw[row0 + tid]; }
  }

  f32x16 acc[2];
#pragma unroll
  for (int i = 0; i < 2; ++i) {
#pragma unroll
    for (int r = 0; r < 16; ++r) acc[i][r] = 0.f;
  }

  const unsigned short* Abase = h + (size_t)(row0 + w * 32 + l31) * FDIM + lh * 8;
  int c0 = w * 2, c1 = c0 + 1;
  const unsigned short *D0, *D1;
  if constexpr (PRE) {
    const unsigned short* WdB = wdb + (size_t)e * DMODEL * FDIM;
    D0 = WdB + (size_t)(d0 + ((c0 >> 2) << 5) + l31) * FDIM + ((c0 & 3) << 4) + lh * 8;
    D1 = WdB + (size_t)(d0 + ((c1 >> 2) << 5) + l31) * FDIM + ((c1 & 3) << 4) + lh * 8;
  }

  if constexpr (PRE) {
    u16x8 pa[4], pd[2];
#pragma unroll
    for (int i = 0; i < 4; ++i) pa[i] = *(const u16x8*)(Abase + i * 16);
    pd[0] = *(const u16x8*)D0; pd[1] = *(const u16x8*)D1;
#pragma unroll
    for (int i = 0; i < 4; ++i) *(u16x8*)&Ah[(w * 4 + i) * 512 + lane * 8] = pa[i];
    *(u16x8*)&Bd[c0 * 512 + lane * 8] = pd[0];
    *(u16x8*)&Bd[c1 * 512 + lane * 8] = pd[1];
    __syncthreads();
    for (int ks = 0; ks < FDIM / 64; ++ks) {
      if (ks < FDIM / 64 - 1) {
        int k1 = (ks + 1) * 64;
#pragma unroll
        for (int i = 0; i < 4; ++i) pa[i] = *(const u16x8*)(Abase + k1 + i * 16);
        pd[0] = *(const u16x8*)(D0 + k1); pd[1] = *(const u16x8*)(D1 + k1);
      }
#pragma unroll
      for (int kq = 0; kq < 4; ++kq) {
        bf16x8 a0 = ld_frag(&Ah[((wm * 2 + 0) * 4 + kq) * 512 + lane * 8]);
        bf16x8 a1 = ld_frag(&Ah[((wm * 2 + 1) * 4 + kq) * 512 + lane * 8]);
        bf16x8 vb = ld_frag(&Bd[(wn * 4 + kq) * 512 + lane * 8]);
        acc[0] = __builtin_amdgcn_mfma_f32_32x32x16_bf16(a0, vb, acc[0], 0, 0, 0);
        acc[1] = __builtin_amdgcn_mfma_f32_32x32x16_bf16(a1, vb, acc[1], 0, 0, 0);
      }
      if (ks < FDIM / 64 - 1) {
        __syncthreads();
#pragma unroll
        for (int i = 0; i < 4; ++i) *(u16x8*)&Ah[(w * 4 + i) * 512 + lane * 8] = pa[i];
        *(u16x8*)&Bd[c0 * 512 + lane * 8] = pd[0];
        *(u16x8*)&Bd[c1 * 512 + lane * 8] = pd[1];
        __syncthreads();
      }
    }
  } else {
    const float* Wd = wd32 + (size_t)e * DMODEL * FDIM;
    for (int ks = 0; ks < FDIM / 64; ++ks) {
      int k0 = ks * 64;
      if (ks) __syncthreads();
#pragma unroll
      for (int i = 0; i < 4; ++i) {
        u16x8 va = *(const u16x8*)(Abase + k0 + i * 16);
        *(u16x8*)&Ah[(w * 4 + i) * 512 + lane * 8] = va;
      }
#pragma unroll
      for (int i2 = 0; i2 < 2; ++i2) {
        int tau = tid + 256 * i2;
        int c = tau >> 6, l = tau & 63;
        int drow = d0 + ((c >> 2) << 5) + (l & 31);
        int kk = k0 + ((c & 3) << 4) + ((l >> 5) << 3);
        const float* sd = Wd + (size_t)drow * FDIM + kk;
        float4 b0 = *(const float4*)sd;
        float4 b1 = *(const float4*)(sd + 4);
        u16x8 vb = {f2bf(b0.x), f2bf(b0.y), f2bf(b0.z), f2bf(b0.w),
                    f2bf(b1.x), f2bf(b1.y), f2bf(b1.z), f2bf(b1.w)};
        *(u16x8*)&Bd[c * 512 + l * 8] = vb;
      }
      __syncthreads();
#pragma unroll
      for (int kq = 0; kq < 4; ++kq) {
        bf16x8 a0 = ld_frag(&Ah[((wm * 2 + 0) * 4 + kq) * 512 + lane * 8]);
        bf16x8 a1 = ld_frag(&Ah[((wm * 2 + 1) * 4 + kq) * 512 + lane * 8]);
        bf16x8 vb = ld_frag(&Bd[(wn * 4 + kq) * 512 + lane * 8]);
        acc[0] = __builtin_amdgcn_mfma_f32_32x32x16_bf16(a0, vb, acc[0], 0, 0, 0);
        acc[1] = __builtin_amdgcn_mfma_f32_32x32x16_bf16(a1, vb, acc[1], 0, 0, 0);
      }
    }
  }
  int col = d0 + wn * 32 + l31;
#pragma unroll
  for (int mt = 0; mt < 2; ++mt) {
#pragma unroll
    for (int r = 0; r < 16; ++r) {
      int lrow = wm * 64 + mt * 32 + (r & 3) + ((r >> 2) << 3) + lh * 4;
      if constexpr (PRE) {
        pv[(size_t)(row0 + lrow) * DMODEL + col] = acc[mt][r];
      } else {
        int t = stok[lrow];
        if (t >= 0) atomicAdd(&out[(size_t)t * DMODEL + col], acc[mt][r] * sw[lrow]);
      }
    }
  }
}

// ---------------- combine: out[t] = w1*pv[r1] + w2*pv[r2] --------------------------
__global__ void k_combine(const float* __restrict__ pv, const int* __restrict__ rpos,
                          const float* __restrict__ tkw, float* __restrict__ out) {
  int t = blockIdx.x;
  int r1 = rpos[2 * t], r2 = rpos[2 * t + 1];
  float w1 = tkw[2 * t], w2 = tkw[2 * t + 1];
  int c = threadIdx.x << 2;
  float4 a = *(const float4*)(pv + (size_t)r1 * DMODEL + c);
  float4 b = *(const float4*)(pv + (size_t)r2 * DMODEL + c);
  float4 o;
  o.x = w1 * a.x + w2 * b.x;
  o.y = w1 * a.y + w2 * b.y;
  o.z = w1 * a.z + w2 * b.z;
  o.w = w1 * a.w + w2 * b.w;
  *(float4*)(out + (size_t)t * DMODEL + c) = o;
}

// ---------------- launch ----------------
extern "C" void kernel_launch(void* const* d_in, const int* in_sizes, int n_in,
                              void* d_out, int out_size, void* d_ws, size_t ws_size,
                              hipStream_t stream) {
  const float* x  = (const float*)d_in[0];
  const float* gw = (const float*)d_in[1];
  const float* wg = (const float*)d_in[2];
  const float* wu = (const float*)d_in[3];
  const float* wd = (const float*)d_in[4];
  float* out = (float*)d_out;
  float* logits = out + OUT_MAIN;

  char* wsb = (char*)d_ws;
  int* meta = (int*)(wsb + OFF_META);
  int* tk_e = (int*)(wsb + OFF_TKE);
  float* tk_w = (float*)(wsb + OFF_TKW);
  int* ptok = (int*)(wsb + OFF_PTOK);
  float* pw = (float*)(wsb + OFF_PW);
  unsigned short* xg = (unsigned short*)(wsb + OFF_XG);
  unsigned short* h = (unsigned short*)(wsb + OFF_H);
  unsigned short* wgb = (unsigned short*)(wsb + OFF_WGB);
  unsigned short* wub = (unsigned short*)(wsb + OFF_WUB);
  unsigned short* wdb = (unsigned short*)(wsb + OFF_WDB);
  float* pv = (float*)(wsb + OFF_PV);
  int* rpos = (int*)(wsb + OFF_RPOS);

  bool pre = ws_size >= (size_t)WS_NEED;
  if (!pre) hipMemsetAsync(out, 0, (size_t)OUT_MAIN * sizeof(float), stream);

  k_prep<<<25600, 256, 0, stream>>>(wg, wu, wd, wgb, wub, wdb, x, gw, logits,
                                    tk_e, tk_w, (int)pre);
  k_route2<<<1, 256, 0, stream>>>(tk_e, tk_w, meta, ptok, pw, rpos);
  k_gather<<<MAXP, 256, 0, stream>>>(x, ptok, xg);
  if (pre) {
    k_gu<true><<<dim3(FDIM / 64, MAXT), 256, 0, stream>>>(xg, wg, wu, wgb, wub, h, meta);
    k_down<true><<<dim3(DMODEL / 64, MAXT), 256, 0, stream>>>(h, wd, wdb, out, pv, meta, ptok, pw);
    k_combine<<<TOK, 256, 0, stream>>>(pv, rpos, tk_w, out);
  } else {
    k_gu<false><<<dim3(FDIM / 64, MAXT), 256, 0, stream>>>(xg, wg, wu, wgb, wub, h, meta);
    k_down<false><<<dim3(DMODEL / 64, MAXT), 256, 0, stream>>>(h, wd, wdb, out, pv, meta, ptok, pw);
  }
}